// Round 7
// baseline (171.026 us; speedup 1.0000x reference)
//
#include <hip/hip_runtime.h>
#include <hip/hip_bf16.h>
#include <math.h>

// Problem constants
#define BT   2048      // B*T tokens
#define DD   1024      // model dim
#define HH   2048      // hidden dim
#define EE   8         // experts
#define CAP  512       // expert capacity = floor(BT*0.25)

typedef unsigned short u16;
typedef unsigned int   u32;
typedef short bf16x8 __attribute__((ext_vector_type(8)));   // 8 bf16 (4 VGPRs) MFMA frag
typedef float f32x4  __attribute__((ext_vector_type(4)));   // MFMA accumulator
typedef u16   u16x4  __attribute__((ext_vector_type(4)));
typedef u16   u16x8  __attribute__((ext_vector_type(8)));
typedef u32   u32x4  __attribute__((ext_vector_type(4)));

#define AS1 __attribute__((address_space(1)))
#define AS3 __attribute__((address_space(3)))

__device__ __forceinline__ u16 f2bf(float f) {   // RNE fp32->bf16
    union { float f; u32 u; } v; v.f = f;
    return (u16)((v.u + 0x7fffu + ((v.u >> 16) & 1u)) >> 16);
}
__device__ __forceinline__ float bf2f(u16 b) {   // exact bf16->fp32
    union { u32 u; float f; } v; v.u = ((u32)b) << 16;
    return v.f;
}
// pack two fp32 -> two bf16 in one u32 (RNE), gfx950 HW instr (no builtin)
__device__ __forceinline__ u32 pkbf(float lo, float hi) {
    u32 r;
    asm("v_cvt_pk_bf16_f32 %0, %1, %2" : "=v"(r) : "v"(lo), "v"(hi));
    return r;
}

// ---------------------------------------------------------------------------
// 1. Router (fp32, exact): scores = x @ rw + rb ; top-2 ; softmax gates
// ---------------------------------------------------------------------------
__global__ __launch_bounds__(256) void router_kernel(
    const float* __restrict__ x, const float* __restrict__ rw,
    const float* __restrict__ rb, int2* __restrict__ assign,
    float2* __restrict__ gates)
{
    int t   = blockIdx.x;
    int tid = threadIdx.x;
    const float* xr = x + (size_t)t * DD;

    float p[EE];
    #pragma unroll
    for (int e = 0; e < EE; ++e) p[e] = 0.f;

    for (int d = tid; d < DD; d += 256) {
        float xv = xr[d];
        const float4* wr = (const float4*)(rw + (size_t)d * EE);
        float4 w0 = wr[0], w1 = wr[1];
        p[0] += xv * w0.x; p[1] += xv * w0.y; p[2] += xv * w0.z; p[3] += xv * w0.w;
        p[4] += xv * w1.x; p[5] += xv * w1.y; p[6] += xv * w1.z; p[7] += xv * w1.w;
    }
    #pragma unroll
    for (int off = 32; off; off >>= 1) {
        #pragma unroll
        for (int e = 0; e < EE; ++e) p[e] += __shfl_down(p[e], off);
    }
    __shared__ float red[4][EE];
    int wv = tid >> 6, ln = tid & 63;
    if (ln == 0) {
        #pragma unroll
        for (int e = 0; e < EE; ++e) red[wv][e] = p[e];
    }
    __syncthreads();
    if (tid == 0) {
        float s[EE];
        #pragma unroll
        for (int e = 0; e < EE; ++e)
            s[e] = red[0][e] + red[1][e] + red[2][e] + red[3][e] + rb[e];
        int i0 = 0;
        #pragma unroll
        for (int e = 1; e < EE; ++e) if (s[e] > s[i0]) i0 = e;
        int i1 = -1;
        #pragma unroll
        for (int e = 0; e < EE; ++e) {
            if (e == i0) continue;
            if (i1 < 0 || s[e] > s[i1]) i1 = e;
        }
        float e1 = expf(s[i1] - s[i0]);
        float denom = 1.0f + e1;
        assign[t] = make_int2(i0, i1);
        gates[t]  = make_float2(1.0f / denom, e1 / denom);
    }
}

// ---------------------------------------------------------------------------
// 2. Scan (exact reference cumsum semantics — verified round 1)
// ---------------------------------------------------------------------------
__global__ __launch_bounds__(64) void scan_kernel(
    const int2* __restrict__ assign, int4* __restrict__ meta,
    int2* __restrict__ slot_tok)
{
    __shared__ int c0[64][EE];
    __shared__ int cA[64][EE];
    int l = threadIdx.x;

    for (int i = l; i < EE * CAP; i += 64) slot_tok[i] = make_int2(-1, -1);
    #pragma unroll
    for (int e = 0; e < EE; ++e) { c0[l][e] = 0; cA[l][e] = 0; }
    __syncthreads();

    const int CH = BT / 64;
    int t0 = l * CH;

    for (int t = t0; t < t0 + CH; ++t) {
        int2 a = assign[t];
        c0[l][a.x]++; cA[l][a.x]++; cA[l][a.y]++;
    }
    __syncthreads();

    #pragma unroll
    for (int e = 0; e < EE; ++e) {
        int v = c0[l][e], inc = v;
        for (int d = 1; d < 64; d <<= 1) { int u = __shfl_up(inc, d); if (l >= d) inc += u; }
        c0[l][e] = inc - v;
        v = cA[l][e]; inc = v;
        for (int d = 1; d < 64; d <<= 1) { int u = __shfl_up(inc, d); if (l >= d) inc += u; }
        cA[l][e] = inc - v;
    }
    __syncthreads();

    for (int t = t0; t < t0 + CH; ++t) {
        int2 a = assign[t];
        int p0 = ++c0[l][a.x];  cA[l][a.x]++;
        int p1 = ++cA[l][a.y];
        int4 m;
        m.x = a.x; m.y = (p0 < CAP) ? p0 : -1;
        m.z = a.y; m.w = (p1 < CAP) ? p1 : -1;
        meta[t] = m;
        int* st = (int*)slot_tok;
        if (p0 < CAP) st[(a.x * CAP + p0) * 2 + 0] = t;
        if (p1 < CAP) st[(a.y * CAP + p1) * 2 + 1] = t;
    }
}

// ---------------------------------------------------------------------------
// 3. Gather -> bf16 grouped (E, CAP, DD)
// ---------------------------------------------------------------------------
__global__ __launch_bounds__(256) void gather_bf16(
    const float* __restrict__ x, const int2* __restrict__ slot_tok,
    u16* __restrict__ G)
{
    int es = blockIdx.x;
    int d  = threadIdx.x * 4;
    int2 st = slot_tok[es];
    float4 r = make_float4(0.f, 0.f, 0.f, 0.f);
    if (st.x >= 0) r = *(const float4*)(x + (size_t)st.x * DD + d);
    if (st.y >= 0) {
        float4 v = *(const float4*)(x + (size_t)st.y * DD + d);
        r.x += v.x; r.y += v.y; r.z += v.z; r.w += v.w;
    }
    u16x4 o;
    o[0] = f2bf(r.x); o[1] = f2bf(r.y); o[2] = f2bf(r.z); o[3] = f2bf(r.w);
    *(u16x4*)(G + (size_t)es * DD + d) = o;
}

// ---------------------------------------------------------------------------
// 4. transpose_cvt: all 3 weights in one dispatch, fp32 (E,R,C) -> bf16 (E,C,R).
//    64x64 tile per block, 256 threads.
//    LDS: u32 T[64][32], u32-col XOR swizzle  col' = col ^ (((r^(r>>4))&7)<<2)
//      - write: 2x ds_write_b128 per thread (16B aligned; b128 bank floor)
//      - read : b32 column reads, <=2 addrs/bank = free
//    Load side: float4 x4 coalesced; pack via v_cvt_pk_bf16_f32.
//    Store side: 2x global_store_dwordx4 per thread, rows 128B-coalesced.
// ---------------------------------------------------------------------------
__device__ __forceinline__ int txs(int r) { return ((r ^ (r >> 4)) & 7) << 2; }

__global__ __launch_bounds__(256) void transpose_cvt(
    const float* __restrict__ w1, const float* __restrict__ w2,
    const float* __restrict__ w3,
    u16* __restrict__ w1t, u16* __restrict__ w2t, u16* __restrict__ w3t)
{
    __shared__ u32 T[64 * 32];
    const int z = blockIdx.y;
    const float* src; u16* dst; int C, shift;
    if (z < EE)           { src = w1 + (size_t)z * DD * HH;        dst = w1t + (size_t)z * DD * HH;        C = HH; shift = 5; }
    else if (z < 2 * EE)  { src = w2 + (size_t)(z - EE) * DD * HH; dst = w2t + (size_t)(z - EE) * DD * HH; C = HH; shift = 5; }
    else                  { src = w3 + (size_t)(z - 16) * HH * DD; dst = w3t + (size_t)(z - 16) * HH * DD; C = DD; shift = 4; }
    const int R  = (shift == 5) ? DD : HH;
    const int bx = blockIdx.x;
    const int c0 = (bx & ((C >> 6) - 1)) << 6;
    const int r0 = (bx >> shift) << 6;
    const int t  = threadIdx.x;

    {   // load + convert + swizzled vector LDS write
        const int r  = t >> 2;
        const int cb = (t & 3) * 8;                 // u32 col base (covers 16 fp32 cols)
        const float4* sp = (const float4*)(src + (size_t)(r0 + r) * C + c0 + cb * 2);
        u32 p[8];
        #pragma unroll
        for (int j = 0; j < 4; ++j) {
            float4 v = sp[j];
            p[2 * j]     = pkbf(v.x, v.y);
            p[2 * j + 1] = pkbf(v.z, v.w);
        }
        const int s = txs(r);
        u32* row = T + r * 32;
        *(u32x4*)(row + ((cb)     ^ s)) = *(u32x4*)&p[0];
        *(u32x4*)(row + ((cb + 4) ^ s)) = *(u32x4*)&p[4];
    }
    __syncthreads();
    {   // column read + pair repack + coalesced store
        const int n  = t >> 2;             // output row (source col) 0..63
        const int cp = n >> 1;             // u32 col holding (2cp, 2cp+1)
        const int rq = (t & 3) * 16;
        const int hi = n & 1;
        u32 q[8];
        #pragma unroll
        for (int i = 0; i < 8; ++i) {
            const int ra = rq + 2 * i;
            const int rb = ra + 1;
            u32 a = T[ra * 32 + (cp ^ txs(ra))];
            u32 b = T[rb * 32 + (cp ^ txs(rb))];
            q[i] = hi ? ((a >> 16) | (b & 0xffff0000u))
                      : ((a & 0xffffu) | (b << 16));
        }
        u16* dp = dst + (size_t)(c0 + n) * R + r0 + rq;
        *(u32x4*)dp       = *(u32x4*)&q[0];
        *(u32x4*)(dp + 8) = *(u32x4*)&q[4];
    }
}

// ---------------------------------------------------------------------------
// LDS XOR-swizzle for GEMMs (T2, rule #21, verified round 4): linear
// global_load_lds dest + pre-swizzled global SOURCE + swizzled READ.
// ---------------------------------------------------------------------------

// ---------------------------------------------------------------------------
// 5. GEMM1 (MFMA): H = gelu((G@w1t^T)*(G@w2t^T)) ; tiles 128x128, BK=32
// ---------------------------------------------------------------------------
__global__ __launch_bounds__(256, 2) void gemm1_mfma(
    const u16* __restrict__ G, const u16* __restrict__ B1t,
    const u16* __restrict__ B2t, u16* __restrict__ H)
{
    __shared__ u16 As [128 * 32];
    __shared__ u16 B1s[128 * 32];
    __shared__ u16 B2s[128 * 32];

    const int e  = blockIdx.z;
    const int n0 = blockIdx.x * 128;
    const int m0 = blockIdx.y * 128;
    const int tid  = threadIdx.x;
    const int lane = tid & 63;
    const int w    = tid >> 6;
    const int wr = w >> 1, wc = w & 1;
    const int lr = lane & 15, lq = lane >> 4;

    const char* Ab  = (const char*)(G   + (size_t)e * CAP * DD + (size_t)m0 * DD);
    const char* B1b = (const char*)(B1t + (size_t)e * HH  * DD + (size_t)n0 * DD);
    const char* B2b = (const char*)(B2t + (size_t)e * HH  * DD + (size_t)n0 * DD);

    const int srow = lane >> 2;                                  // row in chunk
    const int skb  = ((lane & 3) ^ ((lane >> 3) & 3)) * 16;      // pre-swizzled k-slot

    f32x4 acc1[4][4] = {};
    f32x4 acc2[4][4] = {};

    for (int k0 = 0; k0 < DD; k0 += 32) {
        const size_t kbyte = (size_t)k0 * 2 + skb;
        #pragma unroll
        for (int c2 = 0; c2 < 2; ++c2) {
            const int c = 2 * w + c2;                       // chunk 0..7
            const size_t rb = (size_t)(c * 16 + srow) * (DD * 2) + kbyte;
            __builtin_amdgcn_global_load_lds((const AS1 void*)(Ab  + rb),
                (AS3 void*)((char*)As  + c * 1024), 16, 0, 0);
            __builtin_amdgcn_global_load_lds((const AS1 void*)(B1b + rb),
                (AS3 void*)((char*)B1s + c * 1024), 16, 0, 0);
            __builtin_amdgcn_global_load_lds((const AS1 void*)(B2b + rb),
                (AS3 void*)((char*)B2s + c * 1024), 16, 0, 0);
        }
        __syncthreads();
        bf16x8 av[4], b1v[4], b2v[4];
        #pragma unroll
        for (int m = 0; m < 4; ++m) {
            const int row = wr*64 + m*16 + lr;
            const int sl  = (lq ^ ((row >> 1) & 3)) * 16;
            av[m] = *(const bf16x8*)((const char*)As + row * 64 + sl);
        }
        #pragma unroll
        for (int n = 0; n < 4; ++n) {
            const int row = wc*64 + n*16 + lr;
            const int sl  = (lq ^ ((row >> 1) & 3)) * 16;
            b1v[n] = *(const bf16x8*)((const char*)B1s + row * 64 + sl);
            b2v[n] = *(const bf16x8*)((const char*)B2s + row * 64 + sl);
        }
        #pragma unroll
        for (int m = 0; m < 4; ++m)
            #pragma unroll
            for (int n = 0; n < 4; ++n) {
                acc1[m][n] = __builtin_amdgcn_mfma_f32_16x16x32_bf16(av[m], b1v[n], acc1[m][n], 0, 0, 0);
                acc2[m][n] = __builtin_amdgcn_mfma_f32_16x16x32_bf16(av[m], b2v[n], acc2[m][n], 0, 0, 0);
            }
        __syncthreads();
    }

    u16* He = H + (size_t)e * CAP * HH;
    const int r0 = m0 + wr * 64 + lq * 4;
    const int c0 = n0 + wc * 64 + lr;
    const float gc0 = 0.7978845608028654f, gc1 = 0.044715f;
    #pragma unroll
    for (int m = 0; m < 4; ++m)
        #pragma unroll
        for (int n = 0; n < 4; ++n)
            #pragma unroll
            for (int r = 0; r < 4; ++r) {
                float hv = acc1[m][n][r] * acc2[m][n][r];
                float u  = gc0 * (hv + gc1 * hv * hv * hv);
                float th = 1.f - 2.f / (__expf(2.f * u) + 1.f);   // tanh(u)
                He[(size_t)(r0 + m*16 + r) * HH + (c0 + n*16)] = f2bf(0.5f * hv * (1.f + th));
            }
}

// ---------------------------------------------------------------------------
// 6. GEMM2 (MFMA): EO = H @ w3 ; A = H bf16 (CAP,HH); B = w3t (DD rows, HH k)
// ---------------------------------------------------------------------------
__global__ __launch_bounds__(256, 2) void gemm2_mfma(
    const u16* __restrict__ Hin, const u16* __restrict__ B3t, u16* __restrict__ EO)
{
    __shared__ u16 As[128 * 32];
    __shared__ u16 Bs[128 * 32];

    const int e  = blockIdx.z;
    const int n0 = blockIdx.x * 128;
    const int m0 = blockIdx.y * 128;
    const int tid  = threadIdx.x;
    const int lane = tid & 63;
    const int w    = tid >> 6;
    const int wr = w >> 1, wc = w & 1;
    const int lr = lane & 15, lq = lane >> 4;

    const char* Ab = (const char*)(Hin + (size_t)e * CAP * HH + (size_t)m0 * HH);
    const char* Bb = (const char*)(B3t + (size_t)e * DD  * HH + (size_t)n0 * HH);

    const int srow = lane >> 2;
    const int skb  = ((lane & 3) ^ ((lane >> 3) & 3)) * 16;

    f32x4 acc[4][4] = {};

    for (int k0 = 0; k0 < HH; k0 += 32) {
        const size_t kbyte = (size_t)k0 * 2 + skb;
        #pragma unroll
        for (int c2 = 0; c2 < 2; ++c2) {
            const int c = 2 * w + c2;
            const size_t rb = (size_t)(c * 16 + srow) * (HH * 2) + kbyte;
            __builtin_amdgcn_global_load_lds((const AS1 void*)(Ab + rb),
                (AS3 void*)((char*)As + c * 1024), 16, 0, 0);
            __builtin_amdgcn_global_load_lds((const AS1 void*)(Bb + rb),
                (AS3 void*)((char*)Bs + c * 1024), 16, 0, 0);
        }
        __syncthreads();
        bf16x8 av[4], bv[4];
        #pragma unroll
        for (int m = 0; m < 4; ++m) {
            const int row = wr*64 + m*16 + lr;
            const int sl  = (lq ^ ((row >> 1) & 3)) * 16;
            av[m] = *(const bf16x8*)((const char*)As + row * 64 + sl);
        }
        #pragma unroll
        for (int n = 0; n < 4; ++n) {
            const int row = wc*64 + n*16 + lr;
            const int sl  = (lq ^ ((row >> 1) & 3)) * 16;
            bv[n] = *(const bf16x8*)((const char*)Bs + row * 64 + sl);
        }
        #pragma unroll
        for (int m = 0; m < 4; ++m)
            #pragma unroll
            for (int n = 0; n < 4; ++n)
                acc[m][n] = __builtin_amdgcn_mfma_f32_16x16x32_bf16(av[m], bv[n], acc[m][n], 0, 0, 0);
        __syncthreads();
    }

    u16* Oe = EO + (size_t)e * CAP * DD;
    const int r0 = m0 + wr * 64 + lq * 4;
    const int c0 = n0 + wc * 64 + lr;
    #pragma unroll
    for (int m = 0; m < 4; ++m)
        #pragma unroll
        for (int n = 0; n < 4; ++n)
            #pragma unroll
            for (int r = 0; r < 4; ++r)
                Oe[(size_t)(r0 + m*16 + r) * DD + (c0 + n*16)] = f2bf(acc[m][n][r]);
}

// ---------------------------------------------------------------------------
// 7. Combine: out[t] = g0*(kept0 ? EO[e0][p0] : x) + g1*(...)   (EO is bf16)
// ---------------------------------------------------------------------------
__global__ __launch_bounds__(256) void combine_kernel(
    const float* __restrict__ x, const u16* __restrict__ EO,
    const int4* __restrict__ meta, const float2* __restrict__ gates,
    float* __restrict__ out)
{
    int t = blockIdx.x;
    int d = threadIdx.x * 4;
    int4  m = meta[t];
    float2 g = gates[t];
    float4 xv = *(const float4*)(x + (size_t)t * DD + d);
    float4 v0 = xv, v1 = xv;
    if (m.y >= 0) {
        u16x4 q = *(const u16x4*)(EO + ((size_t)m.x * CAP + m.y) * DD + d);
        v0 = make_float4(bf2f(q[0]), bf2f(q[1]), bf2f(q[2]), bf2f(q[3]));
    }
    if (m.w >= 0) {
        u16x4 q = *(const u16x4*)(EO + ((size_t)m.z * CAP + m.w) * DD + d);
        v1 = make_float4(bf2f(q[0]), bf2f(q[1]), bf2f(q[2]), bf2f(q[3]));
    }
    float4 r;
    r.x = g.x * v0.x + g.y * v1.x;
    r.y = g.x * v0.y + g.y * v1.y;
    r.z = g.x * v0.z + g.y * v1.z;
    r.w = g.x * v0.w + g.y * v1.w;
    *(float4*)(out + (size_t)t * DD + d) = r;
}

// ---------------------------------------------------------------------------
extern "C" void kernel_launch(void* const* d_in, const int* in_sizes, int n_in,
                              void* d_out, int out_size, void* d_ws, size_t ws_size,
                              hipStream_t stream)
{
    const float* x  = (const float*)d_in[0];
    const float* rw = (const float*)d_in[1];
    const float* rb = (const float*)d_in[2];
    const float* w1 = (const float*)d_in[3];
    const float* w2 = (const float*)d_in[4];
    const float* w3 = (const float*)d_in[5];
    float* out = (float*)d_out;

    char* ws = (char*)d_ws;
    size_t off = 0;
    auto alloc = [&](size_t bytes) { char* p = ws + off; off = (off + bytes + 255) & ~(size_t)255; return p; };

    int2*   assign   = (int2*)  alloc(BT * sizeof(int2));
    float2* gates    = (float2*)alloc(BT * sizeof(float2));
    int4*   meta     = (int4*)  alloc(BT * sizeof(int4));
    int2*   slot_tok = (int2*)  alloc(EE * CAP * sizeof(int2));
    u16*    grouped  = (u16*)   alloc((size_t)EE * CAP * DD * 2);   //  8.4 MB
    u16*    Hbuf     = (u16*)   alloc((size_t)EE * CAP * HH * 2);   // 16.8 MB
    u16*    eo       = (u16*)   alloc((size_t)EE * CAP * DD * 2);   //  8.4 MB
    u16*    w1t      = (u16*)   alloc((size_t)EE * DD * HH * 2);    // 33.6 MB
    u16*    w2t      = (u16*)   alloc((size_t)EE * DD * HH * 2);    // 33.6 MB
    u16*    w3t      = (u16*)   alloc((size_t)EE * HH * DD * 2);    // 33.6 MB
    (void)ws_size;

    // all three weights: fp32 -> bf16 transpose, one dispatch
    transpose_cvt<<<dim3(512, 24), 256, 0, stream>>>(w1, w2, w3, w1t, w2t, w3t);

    router_kernel<<<BT, 256, 0, stream>>>(x, rw, rb, assign, gates);
    scan_kernel<<<1, 64, 0, stream>>>(assign, meta, slot_tok);
    gather_bf16<<<EE * CAP, 256, 0, stream>>>(x, slot_tok, grouped);

    gemm1_mfma<<<dim3(HH / 128, CAP / 128, EE), 256, 0, stream>>>(grouped, w1t, w2t, Hbuf);
    gemm2_mfma<<<dim3(DD / 128, CAP / 128, EE), 256, 0, stream>>>(Hbuf, w3t, eo);

    combine_kernel<<<BT, 256, 0, stream>>>(x, eo, meta, gates, out);
}

// Round 8
// 155.019 us; speedup vs baseline: 1.1033x; 1.1033x over previous
//
#include <hip/hip_runtime.h>
#include <hip/hip_bf16.h>
#include <math.h>

// Problem constants
#define BT   2048      // B*T tokens
#define DD   1024      // model dim
#define HH   2048      // hidden dim
#define EE   8         // experts
#define CAP  512       // expert capacity = floor(BT*0.25)

typedef unsigned short u16;
typedef unsigned int   u32;
typedef short bf16x8 __attribute__((ext_vector_type(8)));   // 8 bf16 (4 VGPRs) MFMA frag
typedef float f32x4  __attribute__((ext_vector_type(4)));   // MFMA accumulator
typedef u16   u16x4  __attribute__((ext_vector_type(4)));

#define AS1 __attribute__((address_space(1)))
#define AS3 __attribute__((address_space(3)))

__device__ __forceinline__ u16 f2bf(float f) {   // RNE fp32->bf16
    union { float f; u32 u; } v; v.f = f;
    return (u16)((v.u + 0x7fffu + ((v.u >> 16) & 1u)) >> 16);
}
__device__ __forceinline__ float bf2f(u16 b) {   // exact bf16->fp32
    union { u32 u; float f; } v; v.u = ((u32)b) << 16;
    return v.f;
}
// pack two fp32 -> two bf16 in one u32 (RNE), gfx950 HW instr (no builtin)
__device__ __forceinline__ u32 pkbf(float lo, float hi) {
    u32 r;
    asm("v_cvt_pk_bf16_f32 %0, %1, %2" : "=v"(r) : "v"(lo), "v"(hi));
    return r;
}

// ---------------------------------------------------------------------------
// 1. Router (fp32, exact): scores = x @ rw + rb ; top-2 ; softmax gates
// ---------------------------------------------------------------------------
__global__ __launch_bounds__(256) void router_kernel(
    const float* __restrict__ x, const float* __restrict__ rw,
    const float* __restrict__ rb, int2* __restrict__ assign,
    float2* __restrict__ gates)
{
    int t   = blockIdx.x;
    int tid = threadIdx.x;
    const float* xr = x + (size_t)t * DD;

    float p[EE];
    #pragma unroll
    for (int e = 0; e < EE; ++e) p[e] = 0.f;

    for (int d = tid; d < DD; d += 256) {
        float xv = xr[d];
        const float4* wr = (const float4*)(rw + (size_t)d * EE);
        float4 w0 = wr[0], w1 = wr[1];
        p[0] += xv * w0.x; p[1] += xv * w0.y; p[2] += xv * w0.z; p[3] += xv * w0.w;
        p[4] += xv * w1.x; p[5] += xv * w1.y; p[6] += xv * w1.z; p[7] += xv * w1.w;
    }
    #pragma unroll
    for (int off = 32; off; off >>= 1) {
        #pragma unroll
        for (int e = 0; e < EE; ++e) p[e] += __shfl_down(p[e], off);
    }
    __shared__ float red[4][EE];
    int wv = tid >> 6, ln = tid & 63;
    if (ln == 0) {
        #pragma unroll
        for (int e = 0; e < EE; ++e) red[wv][e] = p[e];
    }
    __syncthreads();
    if (tid == 0) {
        float s[EE];
        #pragma unroll
        for (int e = 0; e < EE; ++e)
            s[e] = red[0][e] + red[1][e] + red[2][e] + red[3][e] + rb[e];
        int i0 = 0;
        #pragma unroll
        for (int e = 1; e < EE; ++e) if (s[e] > s[i0]) i0 = e;
        int i1 = -1;
        #pragma unroll
        for (int e = 0; e < EE; ++e) {
            if (e == i0) continue;
            if (i1 < 0 || s[e] > s[i1]) i1 = e;
        }
        float e1 = expf(s[i1] - s[i0]);
        float denom = 1.0f + e1;
        assign[t] = make_int2(i0, i1);
        gates[t]  = make_float2(1.0f / denom, e1 / denom);
    }
}

// ---------------------------------------------------------------------------
// 2. Scan (exact reference cumsum semantics — verified round 1)
// ---------------------------------------------------------------------------
__global__ __launch_bounds__(64) void scan_kernel(
    const int2* __restrict__ assign, int4* __restrict__ meta,
    int2* __restrict__ slot_tok)
{
    __shared__ int c0[64][EE];
    __shared__ int cA[64][EE];
    int l = threadIdx.x;

    for (int i = l; i < EE * CAP; i += 64) slot_tok[i] = make_int2(-1, -1);
    #pragma unroll
    for (int e = 0; e < EE; ++e) { c0[l][e] = 0; cA[l][e] = 0; }
    __syncthreads();

    const int CH = BT / 64;
    int t0 = l * CH;

    for (int t = t0; t < t0 + CH; ++t) {
        int2 a = assign[t];
        c0[l][a.x]++; cA[l][a.x]++; cA[l][a.y]++;
    }
    __syncthreads();

    #pragma unroll
    for (int e = 0; e < EE; ++e) {
        int v = c0[l][e], inc = v;
        for (int d = 1; d < 64; d <<= 1) { int u = __shfl_up(inc, d); if (l >= d) inc += u; }
        c0[l][e] = inc - v;
        v = cA[l][e]; inc = v;
        for (int d = 1; d < 64; d <<= 1) { int u = __shfl_up(inc, d); if (l >= d) inc += u; }
        cA[l][e] = inc - v;
    }
    __syncthreads();

    for (int t = t0; t < t0 + CH; ++t) {
        int2 a = assign[t];
        int p0 = ++c0[l][a.x];  cA[l][a.x]++;
        int p1 = ++cA[l][a.y];
        int4 m;
        m.x = a.x; m.y = (p0 < CAP) ? p0 : -1;
        m.z = a.y; m.w = (p1 < CAP) ? p1 : -1;
        meta[t] = m;
        int* st = (int*)slot_tok;
        if (p0 < CAP) st[(a.x * CAP + p0) * 2 + 0] = t;
        if (p1 < CAP) st[(a.y * CAP + p1) * 2 + 1] = t;
    }
}

// ---------------------------------------------------------------------------
// 3. Gather -> bf16 grouped (E, CAP, DD)
// ---------------------------------------------------------------------------
__global__ __launch_bounds__(256) void gather_bf16(
    const float* __restrict__ x, const int2* __restrict__ slot_tok,
    u16* __restrict__ G)
{
    int es = blockIdx.x;
    int d  = threadIdx.x * 4;
    int2 st = slot_tok[es];
    float4 r = make_float4(0.f, 0.f, 0.f, 0.f);
    if (st.x >= 0) r = *(const float4*)(x + (size_t)st.x * DD + d);
    if (st.y >= 0) {
        float4 v = *(const float4*)(x + (size_t)st.y * DD + d);
        r.x += v.x; r.y += v.y; r.z += v.z; r.w += v.w;
    }
    u16x4 o;
    o[0] = f2bf(r.x); o[1] = f2bf(r.y); o[2] = f2bf(r.z); o[3] = f2bf(r.w);
    *(u16x4*)(G + (size_t)es * DD + d) = o;
}

// ---------------------------------------------------------------------------
// LDS layouts:
//  A (bf16, K-contig): 8 chunks x (16 rows x 64 B), linear DMA dest +
//    pre-swizzled SOURCE k-slot; read slot lq ^ ((row>>1)&3).  [verified r4]
//  B (fp32, natural [k=32][n=128] rows): linear DMA dest; wave w stages rows
//    w*8..w*8+7, source chunk pre-XOR c ^ ((w&3)<<2) (wave-uniform, 64B
//    granular).  Fragment read: float at u32 idx k*128 + (n ^ (lq<<4)),
//    k = lq*8+j  ->  2 lanes/bank (free);  inverse of source XOR since
//    (k>>3)&3 == w for the staging wave.  cvt_pk packs 8 fp32 -> bf16x8.
// ---------------------------------------------------------------------------

// ---------------------------------------------------------------------------
// 5. GEMM1 (MFMA): H = gelu((G@w1)*(G@w2)) ; 128x128 tiles, BK=32
//    A = grouped bf16 (CAP,DD); W1/W2 = natural fp32 (DD rows, HH cols)
// ---------------------------------------------------------------------------
__global__ __launch_bounds__(256, 2) void gemm1_mfma(
    const u16* __restrict__ G, const float* __restrict__ W1,
    const float* __restrict__ W2, u16* __restrict__ H)
{
    __shared__ u16   As [128 * 32];      //  8 KB
    __shared__ float B1s[32 * 128];      // 16 KB
    __shared__ float B2s[32 * 128];      // 16 KB

    const int e  = blockIdx.z;
    const int n0 = blockIdx.x * 128;
    const int m0 = blockIdx.y * 128;
    const int tid  = threadIdx.x;
    const int lane = tid & 63;
    const int w    = tid >> 6;
    const int wr = w >> 1, wc = w & 1;
    const int lr = lane & 15, lq = lane >> 4;

    const char* Ab  = (const char*)(G + (size_t)e * CAP * DD + (size_t)m0 * DD);
    const char* W1b = (const char*)(W1 + (size_t)e * DD * HH + n0);
    const char* W2b = (const char*)(W2 + (size_t)e * DD * HH + n0);

    // A staging coords (verified round 4)
    const int srow = lane >> 2;
    const int skb  = ((lane & 3) ^ ((lane >> 3) & 3)) * 16;
    // B staging coords: lane covers 16B chunk (lane&31) of row parity (lane>>5)
    const int brow = lane >> 5;
    const int bso  = ((lane & 31) ^ ((w & 3) << 2)) * 16;   // pre-swizzled src chunk

    f32x4 acc1[4][4] = {};
    f32x4 acc2[4][4] = {};

    for (int k0 = 0; k0 < DD; k0 += 32) {
        // ---- A staging (DMA) ----
        {
            const size_t kbyte = (size_t)k0 * 2 + skb;
            #pragma unroll
            for (int c2 = 0; c2 < 2; ++c2) {
                const int c = 2 * w + c2;
                const size_t rb = (size_t)(c * 16 + srow) * (DD * 2) + kbyte;
                __builtin_amdgcn_global_load_lds((const AS1 void*)(Ab + rb),
                    (AS3 void*)((char*)As + c * 1024), 16, 0, 0);
            }
        }
        // ---- B staging (DMA, fp32 natural rows; wave w -> rows w*8..w*8+7) ----
        #pragma unroll
        for (int i = 0; i < 4; ++i) {
            const int krow = w * 8 + i * 2 + brow;          // tile-local k row
            const size_t sb = (size_t)(k0 + krow) * (HH * 4) + bso;
            char* d1 = (char*)B1s + (w * 8 + i * 2) * 512;
            char* d2 = (char*)B2s + (w * 8 + i * 2) * 512;
            __builtin_amdgcn_global_load_lds((const AS1 void*)(W1b + sb),
                (AS3 void*)d1, 16, 0, 0);
            __builtin_amdgcn_global_load_lds((const AS1 void*)(W2b + sb),
                (AS3 void*)d2, 16, 0, 0);
        }
        __syncthreads();
        // ---- fragments ----
        bf16x8 av[4], b1v[4], b2v[4];
        #pragma unroll
        for (int m = 0; m < 4; ++m) {
            const int row = wr * 64 + m * 16 + lr;
            const int sl  = (lq ^ ((row >> 1) & 3)) * 16;
            av[m] = *(const bf16x8*)((const char*)As + row * 64 + sl);
        }
        #pragma unroll
        for (int n = 0; n < 4; ++n) {
            const int col = (wc * 64 + n * 16 + lr) ^ (lq << 4);
            const float* p1 = B1s + lq * 8 * 128 + col;
            const float* p2 = B2s + lq * 8 * 128 + col;
            union { u32 q[4]; bf16x8 v; } u1, u2;
            #pragma unroll
            for (int j = 0; j < 4; ++j) {
                u1.q[j] = pkbf(p1[(2*j) * 128], p1[(2*j+1) * 128]);
                u2.q[j] = pkbf(p2[(2*j) * 128], p2[(2*j+1) * 128]);
            }
            b1v[n] = u1.v;
            b2v[n] = u2.v;
        }
        #pragma unroll
        for (int m = 0; m < 4; ++m)
            #pragma unroll
            for (int n = 0; n < 4; ++n) {
                acc1[m][n] = __builtin_amdgcn_mfma_f32_16x16x32_bf16(av[m], b1v[n], acc1[m][n], 0, 0, 0);
                acc2[m][n] = __builtin_amdgcn_mfma_f32_16x16x32_bf16(av[m], b2v[n], acc2[m][n], 0, 0, 0);
            }
        __syncthreads();
    }

    u16* He = H + (size_t)e * CAP * HH;
    const int r0 = m0 + wr * 64 + lq * 4;
    const int c0 = n0 + wc * 64 + lr;
    const float gc0 = 0.7978845608028654f, gc1 = 0.044715f;
    #pragma unroll
    for (int m = 0; m < 4; ++m)
        #pragma unroll
        for (int n = 0; n < 4; ++n)
            #pragma unroll
            for (int r = 0; r < 4; ++r) {
                float hv = acc1[m][n][r] * acc2[m][n][r];
                float u  = gc0 * (hv + gc1 * hv * hv * hv);
                float th = 1.f - 2.f / (__expf(2.f * u) + 1.f);   // tanh(u)
                He[(size_t)(r0 + m*16 + r) * HH + (c0 + n*16)] = f2bf(0.5f * hv * (1.f + th));
            }
}

// ---------------------------------------------------------------------------
// 6. GEMM2 (MFMA): EO = H @ w3 ; A = H bf16 (CAP,HH); W3 natural fp32 (HH,DD)
// ---------------------------------------------------------------------------
__global__ __launch_bounds__(256, 2) void gemm2_mfma(
    const u16* __restrict__ Hin, const float* __restrict__ W3, u16* __restrict__ EO)
{
    __shared__ u16   As[128 * 32];       //  8 KB
    __shared__ float Bs[32 * 128];       // 16 KB

    const int e  = blockIdx.z;
    const int n0 = blockIdx.x * 128;
    const int m0 = blockIdx.y * 128;
    const int tid  = threadIdx.x;
    const int lane = tid & 63;
    const int w    = tid >> 6;
    const int wr = w >> 1, wc = w & 1;
    const int lr = lane & 15, lq = lane >> 4;

    const char* Ab  = (const char*)(Hin + (size_t)e * CAP * HH + (size_t)m0 * HH);
    const char* W3b = (const char*)(W3 + (size_t)e * HH * DD + n0);

    const int srow = lane >> 2;
    const int skb  = ((lane & 3) ^ ((lane >> 3) & 3)) * 16;
    const int brow = lane >> 5;
    const int bso  = ((lane & 31) ^ ((w & 3) << 2)) * 16;

    f32x4 acc[4][4] = {};

    for (int k0 = 0; k0 < HH; k0 += 32) {
        {
            const size_t kbyte = (size_t)k0 * 2 + skb;
            #pragma unroll
            for (int c2 = 0; c2 < 2; ++c2) {
                const int c = 2 * w + c2;
                const size_t rb = (size_t)(c * 16 + srow) * (HH * 2) + kbyte;
                __builtin_amdgcn_global_load_lds((const AS1 void*)(Ab + rb),
                    (AS3 void*)((char*)As + c * 1024), 16, 0, 0);
            }
        }
        #pragma unroll
        for (int i = 0; i < 4; ++i) {
            const int krow = w * 8 + i * 2 + brow;
            const size_t sb = (size_t)(k0 + krow) * (DD * 4) + bso;
            char* d3 = (char*)Bs + (w * 8 + i * 2) * 512;
            __builtin_amdgcn_global_load_lds((const AS1 void*)(W3b + sb),
                (AS3 void*)d3, 16, 0, 0);
        }
        __syncthreads();
        bf16x8 av[4], bv[4];
        #pragma unroll
        for (int m = 0; m < 4; ++m) {
            const int row = wr * 64 + m * 16 + lr;
            const int sl  = (lq ^ ((row >> 1) & 3)) * 16;
            av[m] = *(const bf16x8*)((const char*)As + row * 64 + sl);
        }
        #pragma unroll
        for (int n = 0; n < 4; ++n) {
            const int col = (wc * 64 + n * 16 + lr) ^ (lq << 4);
            const float* p3 = Bs + lq * 8 * 128 + col;
            union { u32 q[4]; bf16x8 v; } u3;
            #pragma unroll
            for (int j = 0; j < 4; ++j)
                u3.q[j] = pkbf(p3[(2*j) * 128], p3[(2*j+1) * 128]);
            bv[n] = u3.v;
        }
        #pragma unroll
        for (int m = 0; m < 4; ++m)
            #pragma unroll
            for (int n = 0; n < 4; ++n)
                acc[m][n] = __builtin_amdgcn_mfma_f32_16x16x32_bf16(av[m], bv[n], acc[m][n], 0, 0, 0);
        __syncthreads();
    }

    u16* Oe = EO + (size_t)e * CAP * DD;
    const int r0 = m0 + wr * 64 + lq * 4;
    const int c0 = n0 + wc * 64 + lr;
    #pragma unroll
    for (int m = 0; m < 4; ++m)
        #pragma unroll
        for (int n = 0; n < 4; ++n)
            #pragma unroll
            for (int r = 0; r < 4; ++r)
                Oe[(size_t)(r0 + m*16 + r) * DD + (c0 + n*16)] = f2bf(acc[m][n][r]);
}

// ---------------------------------------------------------------------------
// 7. Combine: out[t] = g0*(kept0 ? EO[e0][p0] : x) + g1*(...)   (EO is bf16)
// ---------------------------------------------------------------------------
__global__ __launch_bounds__(256) void combine_kernel(
    const float* __restrict__ x, const u16* __restrict__ EO,
    const int4* __restrict__ meta, const float2* __restrict__ gates,
    float* __restrict__ out)
{
    int t = blockIdx.x;
    int d = threadIdx.x * 4;
    int4  m = meta[t];
    float2 g = gates[t];
    float4 xv = *(const float4*)(x + (size_t)t * DD + d);
    float4 v0 = xv, v1 = xv;
    if (m.y >= 0) {
        u16x4 q = *(const u16x4*)(EO + ((size_t)m.x * CAP + m.y) * DD + d);
        v0 = make_float4(bf2f(q[0]), bf2f(q[1]), bf2f(q[2]), bf2f(q[3]));
    }
    if (m.w >= 0) {
        u16x4 q = *(const u16x4*)(EO + ((size_t)m.z * CAP + m.w) * DD + d);
        v1 = make_float4(bf2f(q[0]), bf2f(q[1]), bf2f(q[2]), bf2f(q[3]));
    }
    float4 r;
    r.x = g.x * v0.x + g.y * v1.x;
    r.y = g.x * v0.y + g.y * v1.y;
    r.z = g.x * v0.z + g.y * v1.z;
    r.w = g.x * v0.w + g.y * v1.w;
    *(float4*)(out + (size_t)t * DD + d) = r;
}

// ---------------------------------------------------------------------------
extern "C" void kernel_launch(void* const* d_in, const int* in_sizes, int n_in,
                              void* d_out, int out_size, void* d_ws, size_t ws_size,
                              hipStream_t stream)
{
    const float* x  = (const float*)d_in[0];
    const float* rw = (const float*)d_in[1];
    const float* rb = (const float*)d_in[2];
    const float* w1 = (const float*)d_in[3];
    const float* w2 = (const float*)d_in[4];
    const float* w3 = (const float*)d_in[5];
    float* out = (float*)d_out;

    char* ws = (char*)d_ws;
    size_t off = 0;
    auto alloc = [&](size_t bytes) { char* p = ws + off; off = (off + bytes + 255) & ~(size_t)255; return p; };

    int2*   assign   = (int2*)  alloc(BT * sizeof(int2));
    float2* gates    = (float2*)alloc(BT * sizeof(float2));
    int4*   meta     = (int4*)  alloc(BT * sizeof(int4));
    int2*   slot_tok = (int2*)  alloc(EE * CAP * sizeof(int2));
    u16*    grouped  = (u16*)   alloc((size_t)EE * CAP * DD * 2);   //  8.4 MB
    u16*    Hbuf     = (u16*)   alloc((size_t)EE * CAP * HH * 2);   // 16.8 MB
    u16*    eo       = (u16*)   alloc((size_t)EE * CAP * DD * 2);   //  8.4 MB
    (void)ws_size;

    router_kernel<<<BT, 256, 0, stream>>>(x, rw, rb, assign, gates);
    scan_kernel<<<1, 64, 0, stream>>>(assign, meta, slot_tok);
    gather_bf16<<<EE * CAP, 256, 0, stream>>>(x, slot_tok, grouped);

    gemm1_mfma<<<dim3(HH / 128, CAP / 128, EE), 256, 0, stream>>>(grouped, w1, w2, Hbuf);
    gemm2_mfma<<<dim3(DD / 128, CAP / 128, EE), 256, 0, stream>>>(Hbuf, w3, eo);

    combine_kernel<<<BT, 256, 0, stream>>>(x, eo, meta, gates, out);
}

// Round 9
// 149.249 us; speedup vs baseline: 1.1459x; 1.0387x over previous
//
#include <hip/hip_runtime.h>
#include <hip/hip_bf16.h>
#include <math.h>

// Problem constants
#define BT   2048      // B*T tokens
#define DD   1024      // model dim
#define HH   2048      // hidden dim
#define EE   8         // experts
#define CAP  512       // expert capacity = floor(BT*0.25)

typedef unsigned short u16;
typedef unsigned int   u32;
typedef short bf16x8 __attribute__((ext_vector_type(8)));   // 8 bf16 (4 VGPRs) MFMA frag
typedef float f32x4  __attribute__((ext_vector_type(4)));   // MFMA accumulator
typedef u16   u16x4  __attribute__((ext_vector_type(4)));

#define AS1 __attribute__((address_space(1)))
#define AS3 __attribute__((address_space(3)))

__device__ __forceinline__ u16 f2bf(float f) {   // RNE fp32->bf16
    union { float f; u32 u; } v; v.f = f;
    return (u16)((v.u + 0x7fffu + ((v.u >> 16) & 1u)) >> 16);
}
__device__ __forceinline__ float bf2f(u16 b) {   // exact bf16->fp32
    union { u32 u; float f; } v; v.u = ((u32)b) << 16;
    return v.f;
}
// pack two fp32 -> two bf16 in one u32 (RNE), gfx950 HW instr (no builtin)
__device__ __forceinline__ u32 pkbf(float lo, float hi) {
    u32 r;
    asm("v_cvt_pk_bf16_f32 %0, %1, %2" : "=v"(r) : "v"(lo), "v"(hi));
    return r;
}

// ---------------------------------------------------------------------------
// 1. Router (fp32, exact): scores = x @ rw + rb ; top-2 ; softmax gates
// ---------------------------------------------------------------------------
__global__ __launch_bounds__(256) void router_kernel(
    const float* __restrict__ x, const float* __restrict__ rw,
    const float* __restrict__ rb, int2* __restrict__ assign,
    float2* __restrict__ gates)
{
    int t   = blockIdx.x;
    int tid = threadIdx.x;
    const float* xr = x + (size_t)t * DD;

    float p[EE];
    #pragma unroll
    for (int e = 0; e < EE; ++e) p[e] = 0.f;

    for (int d = tid; d < DD; d += 256) {
        float xv = xr[d];
        const float4* wr = (const float4*)(rw + (size_t)d * EE);
        float4 w0 = wr[0], w1 = wr[1];
        p[0] += xv * w0.x; p[1] += xv * w0.y; p[2] += xv * w0.z; p[3] += xv * w0.w;
        p[4] += xv * w1.x; p[5] += xv * w1.y; p[6] += xv * w1.z; p[7] += xv * w1.w;
    }
    #pragma unroll
    for (int off = 32; off; off >>= 1) {
        #pragma unroll
        for (int e = 0; e < EE; ++e) p[e] += __shfl_down(p[e], off);
    }
    __shared__ float red[4][EE];
    int wv = tid >> 6, ln = tid & 63;
    if (ln == 0) {
        #pragma unroll
        for (int e = 0; e < EE; ++e) red[wv][e] = p[e];
    }
    __syncthreads();
    if (tid == 0) {
        float s[EE];
        #pragma unroll
        for (int e = 0; e < EE; ++e)
            s[e] = red[0][e] + red[1][e] + red[2][e] + red[3][e] + rb[e];
        int i0 = 0;
        #pragma unroll
        for (int e = 1; e < EE; ++e) if (s[e] > s[i0]) i0 = e;
        int i1 = -1;
        #pragma unroll
        for (int e = 0; e < EE; ++e) {
            if (e == i0) continue;
            if (i1 < 0 || s[e] > s[i1]) i1 = e;
        }
        float e1 = expf(s[i1] - s[i0]);
        float denom = 1.0f + e1;
        assign[t] = make_int2(i0, i1);
        gates[t]  = make_float2(1.0f / denom, e1 / denom);
    }
}

// ---------------------------------------------------------------------------
// 2. Scan (exact reference cumsum semantics — verified round 1)
// ---------------------------------------------------------------------------
__global__ __launch_bounds__(64) void scan_kernel(
    const int2* __restrict__ assign, int4* __restrict__ meta,
    int2* __restrict__ slot_tok)
{
    __shared__ int c0[64][EE];
    __shared__ int cA[64][EE];
    int l = threadIdx.x;

    for (int i = l; i < EE * CAP; i += 64) slot_tok[i] = make_int2(-1, -1);
    #pragma unroll
    for (int e = 0; e < EE; ++e) { c0[l][e] = 0; cA[l][e] = 0; }
    __syncthreads();

    const int CH = BT / 64;
    int t0 = l * CH;

    for (int t = t0; t < t0 + CH; ++t) {
        int2 a = assign[t];
        c0[l][a.x]++; cA[l][a.x]++; cA[l][a.y]++;
    }
    __syncthreads();

    #pragma unroll
    for (int e = 0; e < EE; ++e) {
        int v = c0[l][e], inc = v;
        for (int d = 1; d < 64; d <<= 1) { int u = __shfl_up(inc, d); if (l >= d) inc += u; }
        c0[l][e] = inc - v;
        v = cA[l][e]; inc = v;
        for (int d = 1; d < 64; d <<= 1) { int u = __shfl_up(inc, d); if (l >= d) inc += u; }
        cA[l][e] = inc - v;
    }
    __syncthreads();

    for (int t = t0; t < t0 + CH; ++t) {
        int2 a = assign[t];
        int p0 = ++c0[l][a.x];  cA[l][a.x]++;
        int p1 = ++cA[l][a.y];
        int4 m;
        m.x = a.x; m.y = (p0 < CAP) ? p0 : -1;
        m.z = a.y; m.w = (p1 < CAP) ? p1 : -1;
        meta[t] = m;
        int* st = (int*)slot_tok;
        if (p0 < CAP) st[(a.x * CAP + p0) * 2 + 0] = t;
        if (p1 < CAP) st[(a.y * CAP + p1) * 2 + 1] = t;
    }
}

// ---------------------------------------------------------------------------
// 3. Gather -> bf16 grouped (E, CAP, DD)
// ---------------------------------------------------------------------------
__global__ __launch_bounds__(256) void gather_bf16(
    const float* __restrict__ x, const int2* __restrict__ slot_tok,
    u16* __restrict__ G)
{
    int es = blockIdx.x;
    int d  = threadIdx.x * 4;
    int2 st = slot_tok[es];
    float4 r = make_float4(0.f, 0.f, 0.f, 0.f);
    if (st.x >= 0) r = *(const float4*)(x + (size_t)st.x * DD + d);
    if (st.y >= 0) {
        float4 v = *(const float4*)(x + (size_t)st.y * DD + d);
        r.x += v.x; r.y += v.y; r.z += v.z; r.w += v.w;
    }
    u16x4 o;
    o[0] = f2bf(r.x); o[1] = f2bf(r.y); o[2] = f2bf(r.z); o[3] = f2bf(r.w);
    *(u16x4*)(G + (size_t)es * DD + d) = o;
}

// ---------------------------------------------------------------------------
// LDS layouts (verified rounds 4/8):
//  A (bf16, K-contig): 8 chunks x (16 rows x 64 B), linear DMA dest +
//    pre-swizzled SOURCE k-slot; read slot lq ^ ((row>>1)&3).
//  B (fp32, natural [k=32][n=128] rows): linear DMA dest; wave w stages rows
//    w*8..w*8+7, source chunk pre-XOR c ^ ((w&3)<<2).  Fragment read: float
//    at u32 idx k*128 + (n ^ (lq<<4)), k = lq*8+j -> 2 lanes/bank (free).
//  Wave shape (this round): wave w owns the 128M x 32N stripe cols
//    w*32..w*32+31 -> per-wave B reads halve (2 n-frags), A-frags = 8.
//  Column k-pairs read as (q[0], q[128]) with pinned per-pair byte offset so
//    the DS combiner can form ds_read2_b32 (offsets 0/512B fit 8-bit dwords).
// ---------------------------------------------------------------------------

// ---------------------------------------------------------------------------
// 5. GEMM1 (MFMA): H = gelu((G@w1)*(G@w2)) ; 128x128 tiles, BK=32
// ---------------------------------------------------------------------------
__global__ __launch_bounds__(256, 2) void gemm1_mfma(
    const u16* __restrict__ G, const float* __restrict__ W1,
    const float* __restrict__ W2, u16* __restrict__ H)
{
    __shared__ u16   As [128 * 32];      //  8 KB
    __shared__ float B1s[32 * 128];      // 16 KB
    __shared__ float B2s[32 * 128];      // 16 KB

    const int e  = blockIdx.z;
    const int n0 = blockIdx.x * 128;
    const int m0 = blockIdx.y * 128;
    const int tid  = threadIdx.x;
    const int lane = tid & 63;
    const int w    = tid >> 6;
    const int lr = lane & 15, lq = lane >> 4;

    const char* Ab  = (const char*)(G + (size_t)e * CAP * DD + (size_t)m0 * DD);
    const char* W1b = (const char*)(W1 + (size_t)e * DD * HH + n0);
    const char* W2b = (const char*)(W2 + (size_t)e * DD * HH + n0);

    // A staging coords (verified round 4)
    const int srow = lane >> 2;
    const int skb  = ((lane & 3) ^ ((lane >> 3) & 3)) * 16;
    // B staging coords (verified round 8)
    const int brow = lane >> 5;
    const int bso  = ((lane & 31) ^ ((w & 3) << 2)) * 16;

    f32x4 acc1[8][2] = {};
    f32x4 acc2[8][2] = {};

    for (int k0 = 0; k0 < DD; k0 += 32) {
        // ---- A staging (DMA) ----
        {
            const size_t kbyte = (size_t)k0 * 2 + skb;
            #pragma unroll
            for (int c2 = 0; c2 < 2; ++c2) {
                const int c = 2 * w + c2;
                const size_t rb = (size_t)(c * 16 + srow) * (DD * 2) + kbyte;
                __builtin_amdgcn_global_load_lds((const AS1 void*)(Ab + rb),
                    (AS3 void*)((char*)As + c * 1024), 16, 0, 0);
            }
        }
        // ---- B staging (DMA, fp32 natural rows; wave w -> rows w*8..w*8+7) ----
        #pragma unroll
        for (int i = 0; i < 4; ++i) {
            const int krow = w * 8 + i * 2 + brow;
            const size_t sb = (size_t)(k0 + krow) * (HH * 4) + bso;
            char* d1 = (char*)B1s + (w * 8 + i * 2) * 512;
            char* d2 = (char*)B2s + (w * 8 + i * 2) * 512;
            __builtin_amdgcn_global_load_lds((const AS1 void*)(W1b + sb),
                (AS3 void*)d1, 16, 0, 0);
            __builtin_amdgcn_global_load_lds((const AS1 void*)(W2b + sb),
                (AS3 void*)d2, 16, 0, 0);
        }
        __syncthreads();
        // ---- A fragments: all 8 row-frags (wave owns full 128 M) ----
        bf16x8 av[8];
        #pragma unroll
        for (int m = 0; m < 8; ++m) {
            const int row = m * 16 + lr;
            const int sl  = (lq ^ ((row >> 1) & 3)) * 16;
            av[m] = *(const bf16x8*)((const char*)As + row * 64 + sl);
        }
        // ---- B fragments (2 per matrix) + MFMA ----
        #pragma unroll
        for (int nf = 0; nf < 2; ++nf) {
            const int col = (w * 32 + nf * 16 + lr) ^ (lq << 4);
            const int cb  = (lq * 1024 + col) * 4;       // byte offset in tile
            union { u32 q[4]; bf16x8 v; } u1, u2;
            #pragma unroll
            for (int i = 0; i < 4; ++i) {
                int o = cb + i * 1024;                   // k-pair (2i, 2i+1)
                asm("" : "+v"(o));                       // pin base for ds_read2
                u1.q[i] = pkbf(*(const float*)((const char*)B1s + o),
                               *(const float*)((const char*)B1s + o + 512));
                u2.q[i] = pkbf(*(const float*)((const char*)B2s + o),
                               *(const float*)((const char*)B2s + o + 512));
            }
            const bf16x8 b1 = u1.v, b2 = u2.v;
            #pragma unroll
            for (int m = 0; m < 8; ++m) {
                acc1[m][nf] = __builtin_amdgcn_mfma_f32_16x16x32_bf16(av[m], b1, acc1[m][nf], 0, 0, 0);
                acc2[m][nf] = __builtin_amdgcn_mfma_f32_16x16x32_bf16(av[m], b2, acc2[m][nf], 0, 0, 0);
            }
        }
        __syncthreads();
    }

    u16* He = H + (size_t)e * CAP * HH;
    const float gc0 = 0.7978845608028654f, gc1 = 0.044715f;
    #pragma unroll
    for (int m = 0; m < 8; ++m)
        #pragma unroll
        for (int nf = 0; nf < 2; ++nf) {
            const int cc = n0 + w * 32 + nf * 16 + lr;
            #pragma unroll
            for (int r = 0; r < 4; ++r) {
                const int rr = m0 + m * 16 + lq * 4 + r;
                float hv = acc1[m][nf][r] * acc2[m][nf][r];
                float u  = gc0 * (hv + gc1 * hv * hv * hv);
                float th = 1.f - 2.f / (__expf(2.f * u) + 1.f);   // tanh(u)
                He[(size_t)rr * HH + cc] = f2bf(0.5f * hv * (1.f + th));
            }
        }
}

// ---------------------------------------------------------------------------
// 6. GEMM2 (MFMA): EO = H @ w3 ; A = H bf16 (CAP,HH); W3 natural fp32 (HH,DD)
// ---------------------------------------------------------------------------
__global__ __launch_bounds__(256, 2) void gemm2_mfma(
    const u16* __restrict__ Hin, const float* __restrict__ W3, u16* __restrict__ EO)
{
    __shared__ u16   As[128 * 32];       //  8 KB
    __shared__ float Bs[32 * 128];       // 16 KB

    const int e  = blockIdx.z;
    const int n0 = blockIdx.x * 128;
    const int m0 = blockIdx.y * 128;
    const int tid  = threadIdx.x;
    const int lane = tid & 63;
    const int w    = tid >> 6;
    const int lr = lane & 15, lq = lane >> 4;

    const char* Ab  = (const char*)(Hin + (size_t)e * CAP * HH + (size_t)m0 * HH);
    const char* W3b = (const char*)(W3 + (size_t)e * HH * DD + n0);

    const int srow = lane >> 2;
    const int skb  = ((lane & 3) ^ ((lane >> 3) & 3)) * 16;
    const int brow = lane >> 5;
    const int bso  = ((lane & 31) ^ ((w & 3) << 2)) * 16;

    f32x4 acc[8][2] = {};

    for (int k0 = 0; k0 < HH; k0 += 32) {
        {
            const size_t kbyte = (size_t)k0 * 2 + skb;
            #pragma unroll
            for (int c2 = 0; c2 < 2; ++c2) {
                const int c = 2 * w + c2;
                const size_t rb = (size_t)(c * 16 + srow) * (HH * 2) + kbyte;
                __builtin_amdgcn_global_load_lds((const AS1 void*)(Ab + rb),
                    (AS3 void*)((char*)As + c * 1024), 16, 0, 0);
            }
        }
        #pragma unroll
        for (int i = 0; i < 4; ++i) {
            const int krow = w * 8 + i * 2 + brow;
            const size_t sb = (size_t)(k0 + krow) * (DD * 4) + bso;
            char* d3 = (char*)Bs + (w * 8 + i * 2) * 512;
            __builtin_amdgcn_global_load_lds((const AS1 void*)(W3b + sb),
                (AS3 void*)d3, 16, 0, 0);
        }
        __syncthreads();
        bf16x8 av[8];
        #pragma unroll
        for (int m = 0; m < 8; ++m) {
            const int row = m * 16 + lr;
            const int sl  = (lq ^ ((row >> 1) & 3)) * 16;
            av[m] = *(const bf16x8*)((const char*)As + row * 64 + sl);
        }
        #pragma unroll
        for (int nf = 0; nf < 2; ++nf) {
            const int col = (w * 32 + nf * 16 + lr) ^ (lq << 4);
            const int cb  = (lq * 1024 + col) * 4;
            union { u32 q[4]; bf16x8 v; } u3;
            #pragma unroll
            for (int i = 0; i < 4; ++i) {
                int o = cb + i * 1024;
                asm("" : "+v"(o));
                u3.q[i] = pkbf(*(const float*)((const char*)Bs + o),
                               *(const float*)((const char*)Bs + o + 512));
            }
            const bf16x8 b3 = u3.v;
            #pragma unroll
            for (int m = 0; m < 8; ++m)
                acc[m][nf] = __builtin_amdgcn_mfma_f32_16x16x32_bf16(av[m], b3, acc[m][nf], 0, 0, 0);
        }
        __syncthreads();
    }

    u16* Oe = EO + (size_t)e * CAP * DD;
    #pragma unroll
    for (int m = 0; m < 8; ++m)
        #pragma unroll
        for (int nf = 0; nf < 2; ++nf) {
            const int cc = n0 + w * 32 + nf * 16 + lr;
            #pragma unroll
            for (int r = 0; r < 4; ++r) {
                const int rr = m0 + m * 16 + lq * 4 + r;
                Oe[(size_t)rr * DD + cc] = f2bf(acc[m][nf][r]);
            }
        }
}

// ---------------------------------------------------------------------------
// 7. Combine: out[t] = g0*(kept0 ? EO[e0][p0] : x) + g1*(...)   (EO is bf16)
// ---------------------------------------------------------------------------
__global__ __launch_bounds__(256) void combine_kernel(
    const float* __restrict__ x, const u16* __restrict__ EO,
    const int4* __restrict__ meta, const float2* __restrict__ gates,
    float* __restrict__ out)
{
    int t = blockIdx.x;
    int d = threadIdx.x * 4;
    int4  m = meta[t];
    float2 g = gates[t];
    float4 xv = *(const float4*)(x + (size_t)t * DD + d);
    float4 v0 = xv, v1 = xv;
    if (m.y >= 0) {
        u16x4 q = *(const u16x4*)(EO + ((size_t)m.x * CAP + m.y) * DD + d);
        v0 = make_float4(bf2f(q[0]), bf2f(q[1]), bf2f(q[2]), bf2f(q[3]));
    }
    if (m.w >= 0) {
        u16x4 q = *(const u16x4*)(EO + ((size_t)m.z * CAP + m.w) * DD + d);
        v1 = make_float4(bf2f(q[0]), bf2f(q[1]), bf2f(q[2]), bf2f(q[3]));
    }
    float4 r;
    r.x = g.x * v0.x + g.y * v1.x;
    r.y = g.x * v0.y + g.y * v1.y;
    r.z = g.x * v0.z + g.y * v1.z;
    r.w = g.x * v0.w + g.y * v1.w;
    *(float4*)(out + (size_t)t * DD + d) = r;
}

// ---------------------------------------------------------------------------
extern "C" void kernel_launch(void* const* d_in, const int* in_sizes, int n_in,
                              void* d_out, int out_size, void* d_ws, size_t ws_size,
                              hipStream_t stream)
{
    const float* x  = (const float*)d_in[0];
    const float* rw = (const float*)d_in[1];
    const float* rb = (const float*)d_in[2];
    const float* w1 = (const float*)d_in[3];
    const float* w2 = (const float*)d_in[4];
    const float* w3 = (const float*)d_in[5];
    float* out = (float*)d_out;

    char* ws = (char*)d_ws;
    size_t off = 0;
    auto alloc = [&](size_t bytes) { char* p = ws + off; off = (off + bytes + 255) & ~(size_t)255; return p; };

    int2*   assign   = (int2*)  alloc(BT * sizeof(int2));
    float2* gates    = (float2*)alloc(BT * sizeof(float2));
    int4*   meta     = (int4*)  alloc(BT * sizeof(int4));
    int2*   slot_tok = (int2*)  alloc(EE * CAP * sizeof(int2));
    u16*    grouped  = (u16*)   alloc((size_t)EE * CAP * DD * 2);   //  8.4 MB
    u16*    Hbuf     = (u16*)   alloc((size_t)EE * CAP * HH * 2);   // 16.8 MB
    u16*    eo       = (u16*)   alloc((size_t)EE * CAP * DD * 2);   //  8.4 MB
    (void)ws_size;

    router_kernel<<<BT, 256, 0, stream>>>(x, rw, rb, assign, gates);
    scan_kernel<<<1, 64, 0, stream>>>(assign, meta, slot_tok);
    gather_bf16<<<EE * CAP, 256, 0, stream>>>(x, slot_tok, grouped);

    gemm1_mfma<<<dim3(HH / 128, CAP / 128, EE), 256, 0, stream>>>(grouped, w1, w2, Hbuf);
    gemm2_mfma<<<dim3(DD / 128, CAP / 128, EE), 256, 0, stream>>>(Hbuf, w3, eo);

    combine_kernel<<<BT, 256, 0, stream>>>(x, eo, meta, gates, out);
}